// Round 1
// baseline (21713.914 us; speedup 1.0000x reference)
//
#include <hip/hip_runtime.h>

#define NPOIS 100000
#define NHYP  50000
#define NNZE  1600000
#define DIM   256

// One 64-lane wave per edge. Lane l owns float4 [l*4 .. l*4+3] of the 256-wide row.
// gather dense[col] (1KB contiguous, coalesced across the wave), scale, scatter-add
// into out[row] via HW global_atomic_add_f32.
__global__ __launch_bounds__(256) void spmm_scatter(
    const int* __restrict__ rows, const int* __restrict__ cols,
    const float* __restrict__ vals, const float* __restrict__ dense,
    float* __restrict__ out, int nnz)
{
    int gid  = blockIdx.x * blockDim.x + threadIdx.x;
    int edge = gid >> 6;
    int lane = gid & 63;
    if (edge >= nnz) return;

    int   r = rows[edge];
    int   c = cols[edge];
    float v = vals[edge];

    float4 x = ((const float4*)(dense + (size_t)c * DIM))[lane];
    float* dst = out + (size_t)r * DIM + lane * 4;
    unsafeAtomicAdd(dst + 0, v * x.x);
    unsafeAtomicAdd(dst + 1, v * x.y);
    unsafeAtomicAdd(dst + 2, v * x.z);
    unsafeAtomicAdd(dst + 3, v * x.w);
}

// embs_out = (relu(msg)*drop1 + prev)*drop2   (elementwise, float4)
__global__ __launch_bounds__(256) void layer_epilogue(
    const float4* __restrict__ msg, const float4* __restrict__ d1,
    const float4* __restrict__ d2,  const float4* __restrict__ prev,
    float4* __restrict__ out, int n4)
{
    int stride = gridDim.x * blockDim.x;
    for (int i = blockIdx.x * blockDim.x + threadIdx.x; i < n4; i += stride) {
        float4 m = msg[i], a = d1[i], b = d2[i], p = prev[i];
        float4 r;
        r.x = (fmaxf(m.x, 0.f) * a.x + p.x) * b.x;
        r.y = (fmaxf(m.y, 0.f) * a.y + p.y) * b.y;
        r.z = (fmaxf(m.z, 0.f) * a.z + p.z) * b.z;
        r.w = (fmaxf(m.w, 0.f) * a.w + p.w) * b.w;
        out[i] = r;
    }
}

// Layer-2 epilogue fused with the softmax-weighted combine.
// embs1 lives in `out` (d_out); read-then-write same index is safe elementwise.
// out = w0*embs0 + w1*embs1 + w2*((relu(msg)*drop1 + embs1)*drop2)
__global__ __launch_bounds__(256) void final_epilogue(
    const float4* __restrict__ msg, const float4* __restrict__ d1,
    const float4* __restrict__ d2,  const float4* __restrict__ embs0,
    const float* __restrict__ attn, float4* __restrict__ out, int n4)
{
    float a0 = attn[0], a1 = attn[1], a2 = attn[2];
    float mx = fmaxf(a0, fmaxf(a1, a2));
    float e0 = __expf(a0 - mx), e1 = __expf(a1 - mx), e2 = __expf(a2 - mx);
    float inv = 1.f / (e0 + e1 + e2);
    float w0 = e0 * inv, w1 = e1 * inv, w2 = e2 * inv;

    int stride = gridDim.x * blockDim.x;
    for (int i = blockIdx.x * blockDim.x + threadIdx.x; i < n4; i += stride) {
        float4 m = msg[i], a = d1[i], b = d2[i], p0 = embs0[i], p1 = out[i];
        float4 r;
        r.x = w0 * p0.x + w1 * p1.x + w2 * ((fmaxf(m.x, 0.f) * a.x + p1.x) * b.x);
        r.y = w0 * p0.y + w1 * p1.y + w2 * ((fmaxf(m.y, 0.f) * a.y + p1.y) * b.y);
        r.z = w0 * p0.z + w1 * p1.z + w2 * ((fmaxf(m.z, 0.f) * a.z + p1.z) * b.z);
        r.w = w0 * p0.w + w1 * p1.w + w2 * ((fmaxf(m.w, 0.f) * a.w + p1.w) * b.w);
        out[i] = r;
    }
}

extern "C" void kernel_launch(void* const* d_in, const int* in_sizes, int n_in,
                              void* d_out, int out_size, void* d_ws, size_t ws_size,
                              hipStream_t stream)
{
    const float* pois      = (const float*)d_in[0];   // [NPOIS, DIM]
    const float* tar_vals  = (const float*)d_in[1];   // [NNZ]
    const float* src_vals  = (const float*)d_in[2];   // [NNZ]
    const float* attn      = (const float*)d_in[3];   // [3]
    const float* drop1     = (const float*)d_in[4];   // [2, NPOIS, DIM]
    const float* drop2     = (const float*)d_in[5];   // [2, NPOIS, DIM]
    const int*   tar_rows  = (const int*)d_in[6];
    const int*   tar_cols  = (const int*)d_in[7];
    const int*   src_rows  = (const int*)d_in[8];
    const int*   src_cols  = (const int*)d_in[9];
    float* out = (float*)d_out;                        // also holds embs1 temporarily

    const size_t ptn = (size_t)NPOIS * DIM;            // 25.6M floats
    float* msg_tar = (float*)d_ws;                     // NHYP*DIM  (51.2 MB)
    float* msg_src = msg_tar + (size_t)NHYP * DIM;     // NPOIS*DIM (102.4 MB)

    const int BLK = 256;
    const int scat_blocks = (NNZE * 64) / BLK;         // 400000 blocks, 1 wave/edge
    const int n4 = (int)(ptn / 4);                     // 6.4M float4
    const int ew_blocks = n4 / BLK;                    // 25000

    // ---- layer 1 ----
    hipMemsetAsync(msg_tar, 0, (size_t)NHYP * DIM * sizeof(float), stream);
    spmm_scatter<<<scat_blocks, BLK, 0, stream>>>(tar_rows, tar_cols, tar_vals, pois, msg_tar, NNZE);
    hipMemsetAsync(msg_src, 0, ptn * sizeof(float), stream);
    spmm_scatter<<<scat_blocks, BLK, 0, stream>>>(src_rows, src_cols, src_vals, msg_tar, msg_src, NNZE);
    // embs1 -> d_out
    layer_epilogue<<<ew_blocks, BLK, 0, stream>>>(
        (const float4*)msg_src, (const float4*)drop1, (const float4*)drop2,
        (const float4*)pois, (float4*)out, n4);

    // ---- layer 2 ----
    hipMemsetAsync(msg_tar, 0, (size_t)NHYP * DIM * sizeof(float), stream);
    spmm_scatter<<<scat_blocks, BLK, 0, stream>>>(tar_rows, tar_cols, tar_vals, out, msg_tar, NNZE);
    hipMemsetAsync(msg_src, 0, ptn * sizeof(float), stream);
    spmm_scatter<<<scat_blocks, BLK, 0, stream>>>(src_rows, src_cols, src_vals, msg_tar, msg_src, NNZE);
    // fused epilogue2 + softmax-weighted combine (reads embs1 from d_out, writes final)
    final_epilogue<<<ew_blocks, BLK, 0, stream>>>(
        (const float4*)msg_src, (const float4*)(drop1 + ptn), (const float4*)(drop2 + ptn),
        (const float4*)pois, attn, (float4*)out, n4);
}

// Round 2
// 1729.504 us; speedup vs baseline: 12.5550x; 12.5550x over previous
//
#include <hip/hip_runtime.h>

#define NPOIS 100000
#define NHYP  50000
#define NNZE  1600000
#define DIM   256

// ===================== CSR build =====================

__global__ __launch_bounds__(256) void hist_kernel(
    const int* __restrict__ tr, const int* __restrict__ sr,
    int* __restrict__ cnt_tar, int* __restrict__ cnt_src, int nnz)
{
    int e = blockIdx.x * blockDim.x + threadIdx.x;
    if (e >= nnz) return;
    atomicAdd(&cnt_tar[tr[e]], 1);
    atomicAdd(&cnt_src[sr[e]], 1);
}

#define SCAN_TILE 1024  // 256 threads x 4 elems

// exclusive scan within 1024-elem tiles; per-tile totals to bsums
__global__ __launch_bounds__(256) void scan_part(
    const int* __restrict__ in, int* __restrict__ out, int* __restrict__ bsums, int n)
{
    __shared__ int lds[256];
    int t = threadIdx.x;
    int base = blockIdx.x * SCAN_TILE + t * 4;
    int v[4];
#pragma unroll
    for (int j = 0; j < 4; ++j) v[j] = (base + j < n) ? in[base + j] : 0;
    int s = v[0] + v[1] + v[2] + v[3];
    lds[t] = s;
    __syncthreads();
    for (int off = 1; off < 256; off <<= 1) {
        int x = (t >= off) ? lds[t - off] : 0;
        __syncthreads();
        lds[t] += x;
        __syncthreads();
    }
    int run = lds[t] - s;  // exclusive prefix for this thread
#pragma unroll
    for (int j = 0; j < 4; ++j) {
        if (base + j < n) out[base + j] = run;
        run += v[j];
    }
    if (t == 255) bsums[blockIdx.x] = lds[255];
}

// single block: exclusive-scan up to 256 tile sums in place
__global__ __launch_bounds__(256) void scan_sums(int* __restrict__ bsums, int nb)
{
    __shared__ int lds[256];
    int t = threadIdx.x;
    int v = (t < nb) ? bsums[t] : 0;
    lds[t] = v;
    __syncthreads();
    for (int off = 1; off < 256; off <<= 1) {
        int x = (t >= off) ? lds[t - off] : 0;
        __syncthreads();
        lds[t] += x;
        __syncthreads();
    }
    if (t < nb) bsums[t] = lds[t] - v;
}

__global__ __launch_bounds__(256) void add_off(
    int* __restrict__ rp, const int* __restrict__ bsums, int n, int total)
{
    int i = blockIdx.x * blockDim.x + threadIdx.x;
    if (i < n) rp[i] += bsums[i >> 10];
    if (i == 0) rp[n] = total;
}

// permute cols/vals into CSR order (cnt must be re-zeroed before this)
__global__ __launch_bounds__(256) void bucket_kernel(
    const int* __restrict__ rows, const int* __restrict__ cols,
    const float* __restrict__ vals, const int* __restrict__ rp,
    int* __restrict__ cnt, int* __restrict__ pc, float* __restrict__ pv, int nnz)
{
    int e = blockIdx.x * blockDim.x + threadIdx.x;
    if (e >= nnz) return;
    int r = rows[e];
    int slot = rp[r] + atomicAdd(&cnt[r], 1);
    pc[slot] = cols[e];
    pv[slot] = vals[e];
}

// ===================== gather SpMM =====================
// one 64-lane wave per output row; lane owns float4 [lane*4..lane*4+3] of the row.
// batch-preload up to 64 (col,val) pairs, broadcast via shfl.

__device__ __forceinline__ float4 gather_row(
    const int* __restrict__ rp, const int* __restrict__ pc, const float* __restrict__ pv,
    const float* __restrict__ dense, int row, int lane)
{
    int s = rp[row], e = rp[row + 1];
    float4 acc = {0.f, 0.f, 0.f, 0.f};
    for (int base = s; base < e; base += 64) {
        int k = base + lane;
        int c = 0;
        float v = 0.f;
        if (k < e) { c = pc[k]; v = pv[k]; }
        int cnt = min(64, e - base);
        for (int j = 0; j < cnt; ++j) {
            int cc = __shfl(c, j);
            float vv = __shfl(v, j);
            float4 x = ((const float4*)(dense + (size_t)cc * DIM))[lane];
            acc.x += vv * x.x;
            acc.y += vv * x.y;
            acc.z += vv * x.z;
            acc.w += vv * x.w;
        }
    }
    return acc;
}

__global__ __launch_bounds__(256) void spmm_gather(
    const int* __restrict__ rp, const int* __restrict__ pc, const float* __restrict__ pv,
    const float* __restrict__ dense, float* __restrict__ out, int nrows)
{
    int wid  = (blockIdx.x * blockDim.x + threadIdx.x) >> 6;
    int lane = threadIdx.x & 63;
    if (wid >= nrows) return;
    float4 acc = gather_row(rp, pc, pv, dense, wid, lane);
    ((float4*)(out + (size_t)wid * DIM))[lane] = acc;
}

// msg_src gather fused with layer-1 epilogue:
// out[r] = (relu(acc)*drop1 + pois[r]) * drop2
__global__ __launch_bounds__(256) void spmm_gather_epi1(
    const int* __restrict__ rp, const int* __restrict__ pc, const float* __restrict__ pv,
    const float* __restrict__ dense, const float4* __restrict__ pois,
    const float4* __restrict__ d1, const float4* __restrict__ d2,
    float4* __restrict__ out, int nrows)
{
    int wid  = (blockIdx.x * blockDim.x + threadIdx.x) >> 6;
    int lane = threadIdx.x & 63;
    if (wid >= nrows) return;
    float4 m = gather_row(rp, pc, pv, dense, wid, lane);
    size_t idx = (size_t)wid * (DIM / 4) + lane;
    float4 a = d1[idx], b = d2[idx], p = pois[idx];
    float4 r;
    r.x = (fmaxf(m.x, 0.f) * a.x + p.x) * b.x;
    r.y = (fmaxf(m.y, 0.f) * a.y + p.y) * b.y;
    r.z = (fmaxf(m.z, 0.f) * a.z + p.z) * b.z;
    r.w = (fmaxf(m.w, 0.f) * a.w + p.w) * b.w;
    out[idx] = r;
}

// msg_src gather fused with layer-2 epilogue + softmax-weighted combine.
// io holds embs1 on entry; final output on exit (same row read->write, safe).
// io[r] = w0*pois[r] + w1*embs1[r] + w2*((relu(acc)*drop1 + embs1[r])*drop2)
__global__ __launch_bounds__(256) void spmm_gather_final(
    const int* __restrict__ rp, const int* __restrict__ pc, const float* __restrict__ pv,
    const float* __restrict__ dense, const float4* __restrict__ pois,
    const float4* __restrict__ d1, const float4* __restrict__ d2,
    const float* __restrict__ attn, float4* __restrict__ io, int nrows)
{
    int wid  = (blockIdx.x * blockDim.x + threadIdx.x) >> 6;
    int lane = threadIdx.x & 63;
    if (wid >= nrows) return;

    float a0 = attn[0], a1 = attn[1], a2 = attn[2];
    float mx = fmaxf(a0, fmaxf(a1, a2));
    float e0 = __expf(a0 - mx), e1 = __expf(a1 - mx), e2 = __expf(a2 - mx);
    float inv = 1.f / (e0 + e1 + e2);
    float w0 = e0 * inv, w1 = e1 * inv, w2 = e2 * inv;

    float4 m = gather_row(rp, pc, pv, dense, wid, lane);
    size_t idx = (size_t)wid * (DIM / 4) + lane;
    float4 a = d1[idx], b = d2[idx], p0 = pois[idx], p1 = io[idx];
    float4 r;
    r.x = w0 * p0.x + w1 * p1.x + w2 * ((fmaxf(m.x, 0.f) * a.x + p1.x) * b.x);
    r.y = w0 * p0.y + w1 * p1.y + w2 * ((fmaxf(m.y, 0.f) * a.y + p1.y) * b.y);
    r.z = w0 * p0.z + w1 * p1.z + w2 * ((fmaxf(m.z, 0.f) * a.z + p1.z) * b.z);
    r.w = w0 * p0.w + w1 * p1.w + w2 * ((fmaxf(m.w, 0.f) * a.w + p1.w) * b.w);
    io[idx] = r;
}

// ===================== launch =====================

extern "C" void kernel_launch(void* const* d_in, const int* in_sizes, int n_in,
                              void* d_out, int out_size, void* d_ws, size_t ws_size,
                              hipStream_t stream)
{
    const float* pois     = (const float*)d_in[0];
    const float* tar_vals = (const float*)d_in[1];
    const float* src_vals = (const float*)d_in[2];
    const float* attn     = (const float*)d_in[3];
    const float* drop1    = (const float*)d_in[4];
    const float* drop2    = (const float*)d_in[5];
    const int*   tar_rows = (const int*)d_in[6];
    const int*   tar_cols = (const int*)d_in[7];
    const int*   src_rows = (const int*)d_in[8];
    const int*   src_cols = (const int*)d_in[9];
    float* out = (float*)d_out;  // holds embs1 between layer 1 and 2

    const size_t ptn = (size_t)NPOIS * DIM;

    // workspace layout (4B units)
    float* msg_tar = (float*)d_ws;                       // NHYP*DIM
    int*   pc_tar  = (int*)(msg_tar + (size_t)NHYP * DIM);  // NNZ
    float* pv_tar  = (float*)(pc_tar + NNZE);            // NNZ
    int*   pc_src  = (int*)(pv_tar + NNZE);              // NNZ
    float* pv_src  = (float*)(pc_src + NNZE);            // NNZ
    int*   rp_tar  = (int*)(pv_src + NNZE);              // NHYP+1
    int*   rp_src  = rp_tar + (NHYP + 1);                // NPOIS+1
    int*   cnt_tar = rp_src + (NPOIS + 1);               // NHYP
    int*   cnt_src = cnt_tar + NHYP;                     // NPOIS
    int*   bsums   = cnt_src + NPOIS;                    // 256

    const int BLK = 256;
    const int nnz_blocks = (NNZE + BLK - 1) / BLK;       // 6250

    // ---- CSR build (once, reused by both layers) ----
    hipMemsetAsync(cnt_tar, 0, (size_t)(NHYP + NPOIS) * sizeof(int), stream);
    hist_kernel<<<nnz_blocks, BLK, 0, stream>>>(tar_rows, src_rows, cnt_tar, cnt_src, NNZE);

    int tb_tar = (NHYP + SCAN_TILE - 1) / SCAN_TILE;     // 49
    scan_part<<<tb_tar, BLK, 0, stream>>>(cnt_tar, rp_tar, bsums, NHYP);
    scan_sums<<<1, BLK, 0, stream>>>(bsums, tb_tar);
    add_off<<<(NHYP + BLK - 1) / BLK, BLK, 0, stream>>>(rp_tar, bsums, NHYP, NNZE);

    int tb_src = (NPOIS + SCAN_TILE - 1) / SCAN_TILE;    // 98
    scan_part<<<tb_src, BLK, 0, stream>>>(cnt_src, rp_src, bsums, NPOIS);
    scan_sums<<<1, BLK, 0, stream>>>(bsums, tb_src);
    add_off<<<(NPOIS + BLK - 1) / BLK, BLK, 0, stream>>>(rp_src, bsums, NPOIS, NNZE);

    hipMemsetAsync(cnt_tar, 0, (size_t)(NHYP + NPOIS) * sizeof(int), stream);
    bucket_kernel<<<nnz_blocks, BLK, 0, stream>>>(tar_rows, tar_cols, tar_vals, rp_tar, cnt_tar, pc_tar, pv_tar, NNZE);
    bucket_kernel<<<nnz_blocks, BLK, 0, stream>>>(src_rows, src_cols, src_vals, rp_src, cnt_src, pc_src, pv_src, NNZE);

    const int gb_hyp = (NHYP * 64 + BLK - 1) / BLK;      // 12500 blocks (4 waves each)
    const int gb_poi = (NPOIS * 64 + BLK - 1) / BLK;     // 25000 blocks

    // ---- layer 1 ----
    spmm_gather<<<gb_hyp, BLK, 0, stream>>>(rp_tar, pc_tar, pv_tar, pois, msg_tar, NHYP);
    spmm_gather_epi1<<<gb_poi, BLK, 0, stream>>>(
        rp_src, pc_src, pv_src, msg_tar,
        (const float4*)pois, (const float4*)drop1, (const float4*)drop2,
        (float4*)out, NPOIS);

    // ---- layer 2 ----
    spmm_gather<<<gb_hyp, BLK, 0, stream>>>(rp_tar, pc_tar, pv_tar, out, msg_tar, NHYP);
    spmm_gather_final<<<gb_poi, BLK, 0, stream>>>(
        rp_src, pc_src, pv_src, msg_tar,
        (const float4*)pois, (const float4*)(drop1 + ptn), (const float4*)(drop2 + ptn),
        attn, (float4*)out, NPOIS);
}

// Round 3
// 1334.841 us; speedup vs baseline: 16.2670x; 1.2957x over previous
//
#include <hip/hip_runtime.h>

#define NPOIS 100000
#define NHYP  50000
#define NNZE  1600000
#define DIM   256

typedef unsigned int uint;

// ---------- bf16 helpers (RNE) ----------
__device__ __forceinline__ uint pack_bf16(float a, float b) {
    uint ua = __float_as_uint(a); ua += 0x7fffu + ((ua >> 16) & 1u);
    uint ub = __float_as_uint(b); ub += 0x7fffu + ((ub >> 16) & 1u);
    return (ua >> 16) | (ub & 0xffff0000u);
}
__device__ __forceinline__ float4 unpack_h(uint2 u) {
    return make_float4(__uint_as_float(u.x << 16), __uint_as_float(u.x & 0xffff0000u),
                       __uint_as_float(u.y << 16), __uint_as_float(u.y & 0xffff0000u));
}

// f32 [n4 float4] -> bf16 [n4 uint2]
__global__ __launch_bounds__(256) void to_h_kernel(
    const float4* __restrict__ in, uint2* __restrict__ out, int n4)
{
    int stride = gridDim.x * blockDim.x;
    for (int i = blockIdx.x * blockDim.x + threadIdx.x; i < n4; i += stride) {
        float4 x = in[i];
        out[i] = make_uint2(pack_bf16(x.x, x.y), pack_bf16(x.z, x.w));
    }
}

// ---------- CSR build ----------
__global__ __launch_bounds__(256) void hist_kernel(
    const int* __restrict__ tr, const int* __restrict__ sr,
    int* __restrict__ cnt_tar, int* __restrict__ cnt_src, int nnz)
{
    int e = blockIdx.x * blockDim.x + threadIdx.x;
    if (e >= nnz) return;
    atomicAdd(&cnt_tar[tr[e]], 1);
    atomicAdd(&cnt_src[sr[e]], 1);
}

#define SCAN_TILE 1024

__global__ __launch_bounds__(256) void scan_part(
    const int* __restrict__ in, int* __restrict__ out, int* __restrict__ bsums, int n)
{
    __shared__ int lds[256];
    int t = threadIdx.x;
    int base = blockIdx.x * SCAN_TILE + t * 4;
    int v[4];
#pragma unroll
    for (int j = 0; j < 4; ++j) v[j] = (base + j < n) ? in[base + j] : 0;
    int s = v[0] + v[1] + v[2] + v[3];
    lds[t] = s;
    __syncthreads();
    for (int off = 1; off < 256; off <<= 1) {
        int x = (t >= off) ? lds[t - off] : 0;
        __syncthreads();
        lds[t] += x;
        __syncthreads();
    }
    int run = lds[t] - s;
#pragma unroll
    for (int j = 0; j < 4; ++j) {
        if (base + j < n) out[base + j] = run;
        run += v[j];
    }
    if (t == 255) bsums[blockIdx.x] = lds[255];
}

__global__ __launch_bounds__(256) void scan_sums(int* __restrict__ bsums, int nb)
{
    __shared__ int lds[256];
    int t = threadIdx.x;
    int v = (t < nb) ? bsums[t] : 0;
    lds[t] = v;
    __syncthreads();
    for (int off = 1; off < 256; off <<= 1) {
        int x = (t >= off) ? lds[t - off] : 0;
        __syncthreads();
        lds[t] += x;
        __syncthreads();
    }
    if (t < nb) bsums[t] = lds[t] - v;
}

__global__ __launch_bounds__(256) void add_off(
    int* __restrict__ rp, const int* __restrict__ bsums, int n, int total)
{
    int i = blockIdx.x * blockDim.x + threadIdx.x;
    if (i < n) rp[i] += bsums[i >> 10];
    if (i == 0) rp[n] = total;
}

// permute (col,val) into packed CSR order
__global__ __launch_bounds__(256) void bucket_packed(
    const int* __restrict__ rows, const int* __restrict__ cols,
    const float* __restrict__ vals, const int* __restrict__ rp,
    int* __restrict__ cnt, uint2* __restrict__ ep, int nnz)
{
    int e = blockIdx.x * blockDim.x + threadIdx.x;
    if (e >= nnz) return;
    int r = rows[e];
    int slot = rp[r] + atomicAdd(&cnt[r], 1);
    ep[slot] = make_uint2((uint)cols[e], __float_as_uint(vals[e]));
}

// ---------- gather SpMM cores ----------
// row is wave-uniform (forced via readfirstlane) -> edge loads become scalar
// (s_load) broadcasts; #pragma unroll 4 gives 4 outstanding vector gathers.

__device__ __forceinline__ float4 gather_h(
    const int* __restrict__ rp, const uint2* __restrict__ ep,
    const uint2* __restrict__ dh, int row, int lane)
{
    int s = rp[row], e = rp[row + 1];
    float4 acc = {0.f, 0.f, 0.f, 0.f};
#pragma unroll 4
    for (int k = s; k < e; ++k) {
        uint2 ev = ep[k];
        float vv = __uint_as_float(ev.y);
        uint2 x = dh[(size_t)ev.x * (DIM / 4) + lane];
        acc.x += vv * __uint_as_float(x.x << 16);
        acc.y += vv * __uint_as_float(x.x & 0xffff0000u);
        acc.z += vv * __uint_as_float(x.y << 16);
        acc.w += vv * __uint_as_float(x.y & 0xffff0000u);
    }
    return acc;
}

__device__ __forceinline__ float4 gather_f(
    const int* __restrict__ rp, const uint2* __restrict__ ep,
    const float4* __restrict__ d4, int row, int lane)
{
    int s = rp[row], e = rp[row + 1];
    float4 acc = {0.f, 0.f, 0.f, 0.f};
#pragma unroll 4
    for (int k = s; k < e; ++k) {
        uint2 ev = ep[k];
        float vv = __uint_as_float(ev.y);
        float4 x = d4[(size_t)ev.x * (DIM / 16) * 4 + lane];
        acc.x += vv * x.x;
        acc.y += vv * x.y;
        acc.z += vv * x.z;
        acc.w += vv * x.w;
    }
    return acc;
}

// hyperedge-side SpMM -> bf16 out. BF16D: dense is bf16 (else f32).
template <bool BF16D>
__global__ __launch_bounds__(256) void spmm_to_h(
    const int* __restrict__ rp, const uint2* __restrict__ ep,
    const void* __restrict__ dense, uint2* __restrict__ out_h, int nrows)
{
    int wid  = (blockIdx.x * blockDim.x + threadIdx.x) >> 6;
    int lane = threadIdx.x & 63;
    if (wid >= nrows) return;
    int row = __builtin_amdgcn_readfirstlane(wid);
    float4 a = BF16D ? gather_h(rp, ep, (const uint2*)dense, row, lane)
                     : gather_f(rp, ep, (const float4*)dense, row, lane);
    out_h[(size_t)row * (DIM / 4) + lane] = make_uint2(pack_bf16(a.x, a.y), pack_bf16(a.z, a.w));
}

// poi-side SpMM + layer-1 epilogue -> embs1 (bf16).
// PH: pois residual from bf16 copy (else f32 original)
template <bool PH>
__global__ __launch_bounds__(256) void spmm_epi1(
    const int* __restrict__ rp, const uint2* __restrict__ ep,
    const uint2* __restrict__ msg_h,
    const uint2* __restrict__ pois_h, const float4* __restrict__ pois_f,
    const float4* __restrict__ d1, const float4* __restrict__ d2,
    uint2* __restrict__ out_h, int nrows)
{
    int wid  = (blockIdx.x * blockDim.x + threadIdx.x) >> 6;
    int lane = threadIdx.x & 63;
    if (wid >= nrows) return;
    int row = __builtin_amdgcn_readfirstlane(wid);
    float4 m = gather_h(rp, ep, msg_h, row, lane);
    size_t idx = (size_t)row * (DIM / 4) + lane;
    float4 a = d1[idx], b = d2[idx];
    float4 p = PH ? unpack_h(pois_h[idx]) : pois_f[idx];
    float4 r;
    r.x = (fmaxf(m.x, 0.f) * a.x + p.x) * b.x;
    r.y = (fmaxf(m.y, 0.f) * a.y + p.y) * b.y;
    r.z = (fmaxf(m.z, 0.f) * a.z + p.z) * b.z;
    r.w = (fmaxf(m.w, 0.f) * a.w + p.w) * b.w;
    out_h[idx] = make_uint2(pack_bf16(r.x, r.y), pack_bf16(r.z, r.w));
}

// poi-side SpMM + layer-2 epilogue + softmax-weighted combine -> f32 out.
template <bool PH>
__global__ __launch_bounds__(256) void spmm_final(
    const int* __restrict__ rp, const uint2* __restrict__ ep,
    const uint2* __restrict__ msg_h,
    const uint2* __restrict__ pois_h, const float4* __restrict__ pois_f,
    const uint2* __restrict__ embs1_h,
    const float4* __restrict__ d1, const float4* __restrict__ d2,
    const float* __restrict__ attn, float4* __restrict__ out, int nrows)
{
    int wid  = (blockIdx.x * blockDim.x + threadIdx.x) >> 6;
    int lane = threadIdx.x & 63;
    if (wid >= nrows) return;
    int row = __builtin_amdgcn_readfirstlane(wid);

    float a0 = attn[0], a1 = attn[1], a2 = attn[2];
    float mx = fmaxf(a0, fmaxf(a1, a2));
    float e0 = __expf(a0 - mx), e1 = __expf(a1 - mx), e2 = __expf(a2 - mx);
    float inv = 1.f / (e0 + e1 + e2);
    float w0 = e0 * inv, w1 = e1 * inv, w2 = e2 * inv;

    float4 m = gather_h(rp, ep, msg_h, row, lane);
    size_t idx = (size_t)row * (DIM / 4) + lane;
    float4 a = d1[idx], b = d2[idx];
    float4 p0 = PH ? unpack_h(pois_h[idx]) : pois_f[idx];
    float4 p1 = unpack_h(embs1_h[idx]);
    float4 r;
    r.x = w0 * p0.x + w1 * p1.x + w2 * ((fmaxf(m.x, 0.f) * a.x + p1.x) * b.x);
    r.y = w0 * p0.y + w1 * p1.y + w2 * ((fmaxf(m.y, 0.f) * a.y + p1.y) * b.y);
    r.z = w0 * p0.z + w1 * p1.z + w2 * ((fmaxf(m.z, 0.f) * a.z + p1.z) * b.z);
    r.w = w0 * p0.w + w1 * p1.w + w2 * ((fmaxf(m.w, 0.f) * a.w + p1.w) * b.w);
    out[idx] = r;
}

// ---------- launch ----------
extern "C" void kernel_launch(void* const* d_in, const int* in_sizes, int n_in,
                              void* d_out, int out_size, void* d_ws, size_t ws_size,
                              hipStream_t stream)
{
    const float* pois     = (const float*)d_in[0];
    const float* tar_vals = (const float*)d_in[1];
    const float* src_vals = (const float*)d_in[2];
    const float* attn     = (const float*)d_in[3];
    const float* drop1    = (const float*)d_in[4];
    const float* drop2    = (const float*)d_in[5];
    const int*   tar_rows = (const int*)d_in[6];
    const int*   tar_cols = (const int*)d_in[7];
    const int*   src_rows = (const int*)d_in[8];
    const int*   src_cols = (const int*)d_in[9];
    float* out = (float*)d_out;

    const size_t ptn = (size_t)NPOIS * DIM;

    // workspace layout (bytes, 16B-aligned chunks)
    char* p = (char*)d_ws;
    uint2* ep_tar   = (uint2*)p;            p += (size_t)NNZE * 8;            // 12.8 MB
    uint2* ep_src   = (uint2*)p;            p += (size_t)NNZE * 8;            // 12.8 MB
    int*   rp_tar   = (int*)p;              p += 200064;                      // NHYP+1
    int*   rp_src   = (int*)p;              p += 400064;                      // NPOIS+1
    uint2* msg_h    = (uint2*)p;            p += (size_t)NHYP * DIM * 2;      // 25.6 MB
    uint2* embs1_h  = (uint2*)p;            p += (size_t)NPOIS * DIM * 2;     // 51.2 MB
    size_t base_need = (size_t)(p - (char*)d_ws);
    uint2* pois_h   = (uint2*)p;                                              // +51.2 MB (optional)
    bool full = ws_size >= base_need + (size_t)NPOIS * DIM * 2;

    // cnt/bsums scratch overlaid in msg_h (unused during CSR build)
    int* cnt_tar = (int*)msg_h;
    int* cnt_src = cnt_tar + NHYP;
    int* bsums   = cnt_src + NPOIS;

    const int BLK = 256;
    const int nnz_blocks = (NNZE + BLK - 1) / BLK;

    // optional f32->bf16 pois copy
    if (full)
        to_h_kernel<<<(int)(ptn / 4 + BLK - 1) / BLK, BLK, 0, stream>>>(
            (const float4*)pois, pois_h, (int)(ptn / 4));

    // ---- CSR build ----
    hipMemsetAsync(cnt_tar, 0, (size_t)(NHYP + NPOIS) * sizeof(int), stream);
    hist_kernel<<<nnz_blocks, BLK, 0, stream>>>(tar_rows, src_rows, cnt_tar, cnt_src, NNZE);

    int tb_tar = (NHYP + SCAN_TILE - 1) / SCAN_TILE;
    scan_part<<<tb_tar, BLK, 0, stream>>>(cnt_tar, rp_tar, bsums, NHYP);
    scan_sums<<<1, BLK, 0, stream>>>(bsums, tb_tar);
    add_off<<<(NHYP + BLK - 1) / BLK, BLK, 0, stream>>>(rp_tar, bsums, NHYP, NNZE);

    int tb_src = (NPOIS + SCAN_TILE - 1) / SCAN_TILE;
    scan_part<<<tb_src, BLK, 0, stream>>>(cnt_src, rp_src, bsums, NPOIS);
    scan_sums<<<1, BLK, 0, stream>>>(bsums, tb_src);
    add_off<<<(NPOIS + BLK - 1) / BLK, BLK, 0, stream>>>(rp_src, bsums, NPOIS, NNZE);

    hipMemsetAsync(cnt_tar, 0, (size_t)(NHYP + NPOIS) * sizeof(int), stream);
    bucket_packed<<<nnz_blocks, BLK, 0, stream>>>(tar_rows, tar_cols, tar_vals, rp_tar, cnt_tar, ep_tar, NNZE);
    bucket_packed<<<nnz_blocks, BLK, 0, stream>>>(src_rows, src_cols, src_vals, rp_src, cnt_src, ep_src, NNZE);

    const int gb_hyp = NHYP / 4;   // 12500 blocks (4 waves each)
    const int gb_poi = NPOIS / 4;  // 25000 blocks

    // ---- layer 1 ----
    if (full)
        spmm_to_h<true><<<gb_hyp, BLK, 0, stream>>>(rp_tar, ep_tar, pois_h, msg_h, NHYP);
    else
        spmm_to_h<false><<<gb_hyp, BLK, 0, stream>>>(rp_tar, ep_tar, pois, msg_h, NHYP);

    if (full)
        spmm_epi1<true><<<gb_poi, BLK, 0, stream>>>(
            rp_src, ep_src, msg_h, pois_h, (const float4*)pois,
            (const float4*)drop1, (const float4*)drop2, embs1_h, NPOIS);
    else
        spmm_epi1<false><<<gb_poi, BLK, 0, stream>>>(
            rp_src, ep_src, msg_h, pois_h, (const float4*)pois,
            (const float4*)drop1, (const float4*)drop2, embs1_h, NPOIS);

    // ---- layer 2 ----
    spmm_to_h<true><<<gb_hyp, BLK, 0, stream>>>(rp_tar, ep_tar, embs1_h, msg_h, NHYP);

    if (full)
        spmm_final<true><<<gb_poi, BLK, 0, stream>>>(
            rp_src, ep_src, msg_h, pois_h, (const float4*)pois, embs1_h,
            (const float4*)(drop1 + ptn), (const float4*)(drop2 + ptn),
            attn, (float4*)out, NPOIS);
    else
        spmm_final<false><<<gb_poi, BLK, 0, stream>>>(
            rp_src, ep_src, msg_h, pois_h, (const float4*)pois, embs1_h,
            (const float4*)(drop1 + ptn), (const float4*)(drop2 + ptn),
            attn, (float4*)out, NPOIS);
}